// Round 4
// baseline (35.004 us; speedup 1.0000x reference)
//
#include <hip/hip_runtime.h>
#include <hip/hip_bf16.h>

// Chamfer min-matching loss, B=8, P=4096, D=2, fp32.
// d2(q,g) = |q|^2 + (|g|^2 - 2 q.g). Per base point precompute hx=-2gx,
// hy=-2gy, c=|g|^2 in LDS. Inner loop is plain fmaf + fminf (compiler emits
// v_fma_f32 + v_min3_f32; no inline asm -> no operand marshaling).
// Cross-chunk min via atomicMin on uint-reinterpreted nonneg fp32.

#define NB    8
#define NP    4096
#define QPT   8
#define NC    32
#define NPC   2              // NP / (256*QPT)
#define CHUNK (NP / NC)      // 128

typedef float f32x4 __attribute__((ext_vector_type(4)));

__global__ __launch_bounds__(256) void chamferA(const float* __restrict__ pred,
                                                const float* __restrict__ gt,
                                                unsigned int* __restrict__ minb) {
    __shared__ __align__(16) float shx[CHUNK];
    __shared__ __align__(16) float shy[CHUNK];
    __shared__ __align__(16) float sc[CHUNK];

    int bid = blockIdx.x;
    int gc  = bid % NC;       bid /= NC;
    int pc  = bid % NPC;      bid /= NPC;
    int b   = bid & (NB - 1);
    int dir = bid >> 3;       // 0: query=pred base=gt ; 1: query=gt base=pred

    const float* query = dir ? gt : pred;
    const float* base  = dir ? pred : gt;

    const float2* base2 = (const float2*)base + (size_t)b * NP + gc * CHUNK;
    int t = threadIdx.x;
    if (t < CHUNK) {                       // CHUNK = 128 <= 256
        float2 g = base2[t];
        shx[t] = -2.0f * g.x;
        shy[t] = -2.0f * g.y;
        sc[t]  = g.x * g.x + g.y * g.y;
    }
    __syncthreads();

    const float2* query2 = (const float2*)query + (size_t)b * NP + pc * (256 * QPT);
    float px[QPT], py[QPT], p2[QPT], m[QPT];
#pragma unroll
    for (int k = 0; k < QPT; ++k) {
        float2 q = query2[t + k * 256];
        px[k] = q.x; py[k] = q.y;
        p2[k] = q.x * q.x + q.y * q.y;
        m[k]  = 3.402823466e+38f;
    }

    const f32x4* hx4 = (const f32x4*)shx;
    const f32x4* hy4 = (const f32x4*)shy;
    const f32x4* cc4 = (const f32x4*)sc;

#pragma unroll 4
    for (int j = 0; j < CHUNK / 4; ++j) {
        f32x4 hx = hx4[j], hy = hy4[j], cc = cc4[j];
#pragma unroll
        for (int k = 0; k < QPT; ++k) {
            float d0 = fmaf(px[k], hx.x, fmaf(py[k], hy.x, cc.x));
            float d1 = fmaf(px[k], hx.y, fmaf(py[k], hy.y, cc.y));
            float d2 = fmaf(px[k], hx.z, fmaf(py[k], hy.z, cc.z));
            float d3 = fmaf(px[k], hx.w, fmaf(py[k], hy.w, cc.w));
            m[k] = fminf(fminf(m[k], d0), d1);   // -> v_min3_f32
            m[k] = fminf(fminf(m[k], d2), d3);   // -> v_min3_f32
        }
    }

    unsigned int* slot = minb + ((size_t)(dir * NB + b)) * NP + pc * (256 * QPT) + t;
#pragma unroll
    for (int k = 0; k < QPT; ++k) {
        float v = fmaxf(m[k] + p2[k], 0.0f);     // nonneg -> uint order == fp order
        atomicMin(&slot[k * 256], __float_as_uint(v));
    }
}

// Single block: read 2*NB*NP mins, sqrt, sum, store. No out-init needed.
__global__ __launch_bounds__(1024) void chamferC(const unsigned int* __restrict__ minb,
                                                 float* __restrict__ out) {
    int t = threadIdx.x;
    const f32x4* p4 = (const f32x4*)minb;        // 16384 float4
    float s = 0.0f;
#pragma unroll
    for (int i = 0; i < 16; ++i) {
        f32x4 v = p4[t + i * 1024];
        s += sqrtf(fmaxf(v.x, 1e-12f)) + sqrtf(fmaxf(v.y, 1e-12f)) +
             sqrtf(fmaxf(v.z, 1e-12f)) + sqrtf(fmaxf(v.w, 1e-12f));
    }
#pragma unroll
    for (int o = 32; o > 0; o >>= 1) s += __shfl_down(s, o, 64);

    __shared__ float wsum[16];
    int lane = t & 63, w = t >> 6;
    if (lane == 0) wsum[w] = s;
    __syncthreads();
    if (t == 0) {
        float tot = 0.0f;
#pragma unroll
        for (int i = 0; i < 16; ++i) tot += wsum[i];
        *out = tot * (0.5f / (float)(NB * NP));
    }
}

extern "C" void kernel_launch(void* const* d_in, const int* in_sizes, int n_in,
                              void* d_out, int out_size, void* d_ws, size_t ws_size,
                              hipStream_t stream) {
    const float* pred = (const float*)d_in[0];
    const float* gt   = (const float*)d_in[1];
    float*       out  = (float*)d_out;
    unsigned int* minb = (unsigned int*)d_ws;

    (void)in_sizes; (void)n_in; (void)out_size; (void)ws_size;

    // init min buffer to 0xFFFFFFFF (> any nonneg float bits); replay-safe.
    hipMemsetAsync(minb, 0xFF, (size_t)2 * NB * NP * sizeof(unsigned int), stream);

    chamferA<<<2 * NB * NPC * NC, 256, 0, stream>>>(pred, gt, minb);
    chamferC<<<1, 1024, 0, stream>>>(minb, out);
}